// Round 7
// baseline (372.118 us; speedup 1.0000x reference)
//
#include <hip/hip_runtime.h>

#define NCOLS 256
#define NP    128
#define DD    256

typedef _Float16 half2 __attribute__((ext_vector_type(2)));
typedef _Float16 half4 __attribute__((ext_vector_type(4)));
typedef float    f32x4 __attribute__((ext_vector_type(4)));

// gfx950 spelling has no underscore before f16 (compiler-confirmed)
#define MFMA16(a,b,c) __builtin_amdgcn_mfma_f32_16x16x16f16(a,b,c,0,0,0)

// ---- workspace layout (bytes) ----
#define WS_COL_LN   0          // f32 [256][256]  LN(emb_column)
#define WS_LNP      262144     // f32 [128][256]  LN(emb_prompt)
#define WS_BASE     393216     // f32 [128][256]  base (prompt-side xp part)
#define WS_BLOG     524288     // f32 [128][256]  base_logits
#define WS_CW16     655360     // f16 CW in MFMA A-fragment order (see k0b)
#define WS_WB16     786432     // half2 [256][256] {w,b} interleaved feature emb

// ---- main-kernel LDS layout ----
#define XE_STRIDE 68           // f16 units; row byte stride 136 (8B aligned)
#define XE0_OFF   3072
#define XE1_OFF   37888
#define SMEM_BYTES 72704       // 2 blocks/CU: 2*72704 = 145408 <= 163840

// ============================ stage 0 kernels ============================

__global__ __launch_bounds__(256) void k0a(
    const float* __restrict__ emb_column, const float* __restrict__ emb_prompt,
    const float* __restrict__ ln_col_g, const float* __restrict__ ln_col_b,
    const float* __restrict__ ln_prompt_g, const float* __restrict__ ln_prompt_b,
    const float* __restrict__ few, const float* __restrict__ feb, char* __restrict__ ws)
{
    __shared__ float red[10];
    int blk = blockIdx.x, tid = threadIdx.x;
    if (blk < 384) {
        const float *src, *g, *bb; float* dst;
        if (blk < 256) { int r = blk;     src = emb_column + r*DD; g = ln_col_g;    bb = ln_col_b;    dst = (float*)(ws + WS_COL_LN) + r*DD; }
        else           { int r = blk-256; src = emb_prompt + r*DD; g = ln_prompt_g; bb = ln_prompt_b; dst = (float*)(ws + WS_LNP) + r*DD; }
        float v = src[tid];
        float s = v, q = v*v;
        #pragma unroll
        for (int off = 32; off; off >>= 1) { s += __shfl_xor(s, off); q += __shfl_xor(q, off); }
        int wid = tid >> 6, lane = tid & 63;
        if (lane == 0) { red[wid] = s; red[4+wid] = q; }
        __syncthreads();
        if (tid == 0) {
            float S = red[0]+red[1]+red[2]+red[3];
            float Q = red[4]+red[5]+red[6]+red[7];
            float mu = S * (1.0f/DD);
            float var = Q * (1.0f/DD) - mu*mu;
            red[8] = mu; red[9] = rsqrtf(var + 1e-5f);
        }
        __syncthreads();
        dst[tid] = (v - red[8]) * red[9] * g[tid] + bb[tid];
    } else {
        int base = (blk - 384) * 512;
        half2* wb = (half2*)(ws + WS_WB16);
        #pragma unroll
        for (int j = 0; j < 2; ++j) {
            int idx = base + j*256 + tid;      // 0..65535
            half2 h; h[0] = (_Float16)few[idx]; h[1] = (_Float16)feb[idx];
            wb[idx] = h;
        }
    }
}

// blocks 0..255: CW[n][k] = sum_d col_ln[n][d] * diw[d][256+k], stored in
//   MFMA A-fragment order: f16 index ((kc*16+nt)*64 + lq*16 + lr)*4 + j
//   with n = 16nt+lr, k = 16kc+4lq+j  -> P1 lane loads become contiguous.
// blocks 256..383: base[p][d] = sum_k LNp[p][k]*diw[d][k] + dib[d] + emb_prompt[p][d]
__global__ __launch_bounds__(256) void k0b(
    const float* __restrict__ diw, const float* __restrict__ dib,
    const float* __restrict__ emb_prompt, char* __restrict__ ws)
{
    __shared__ float rowv[DD];
    int blk = blockIdx.x, tid = threadIdx.x;
    if (blk < 256) {
        int n = blk;
        const float* col_ln = (const float*)(ws + WS_COL_LN);
        rowv[tid] = col_ln[n*DD + tid];
        __syncthreads();
        float acc = 0.f;
        #pragma unroll 4
        for (int d = 0; d < DD; ++d) acc += rowv[d] * diw[d*512 + 256 + tid];
        int nt = n >> 4, lr = n & 15;
        int kc = tid >> 4, lq = (tid >> 2) & 3, j = tid & 3;
        ((_Float16*)(ws + WS_CW16))[((kc*16 + nt)*64 + lq*16 + lr)*4 + j] = (_Float16)acc;
    } else {
        int p = blk - 256;
        const float* lnp = (const float*)(ws + WS_LNP);
        rowv[tid] = lnp[p*DD + tid];
        __syncthreads();
        float acc = 0.f;
        #pragma unroll 4
        for (int k = 0; k < DD; ++k) acc += rowv[k] * diw[tid*512 + k];
        ((float*)(ws + WS_BASE))[p*DD + tid] = acc + dib[tid] + emb_prompt[p*DD + tid];
    }
}

// base_logits[p][n] = sum_d base[p][d] * col_ln[n][d]
__global__ __launch_bounds__(256) void k0c(char* __restrict__ ws)
{
    __shared__ float bs[DD];
    int p = blockIdx.x, n = threadIdx.x;
    const float* base   = (const float*)(ws + WS_BASE);
    const float* col_ln = (const float*)(ws + WS_COL_LN);
    bs[n] = base[p*DD + n];
    __syncthreads();
    float acc = 0.f;
    #pragma unroll 4
    for (int d = 0; d < DD; ++d) acc += bs[d] * col_ln[n*DD + d];
    ((float*)(ws + WS_BLOG))[p*DD + n] = acc;
}

// ============================ main kernel ============================
// grid = 2048: block covers batch b = bid>>1, prompt half ph = bid&1
// (64 p-rows) x all 256 d. 8 waves: wave w -> p-tile (w>>1) in [0,4),
// d-half (w&1). Wave pairs duplicate logits+softmax (wave-local shfl),
// each keeps only a 16p x 128d V accumulator (32 regs) -> permanent
// state acc_v(32)+pfrag(32)=64 regs, fits the 128-unified cap of
// (512,4) without spill. Flash loop over 4 n-chunks of 64.
__global__ __launch_bounds__(512, 4) void trompt_main(
    const float* __restrict__ x, const float* __restrict__ prev,
    const float* __restrict__ expand_w, const float* __restrict__ expand_b,
    const float* __restrict__ ln_emb_g, const float* __restrict__ ln_emb_b,
    const char* __restrict__ ws, float* __restrict__ out)
{
    extern __shared__ char smem[];
    float* x_s  = (float*)(smem);
    float* g_s  = (float*)(smem + 1024);
    float* bb_s = (float*)(smem + 2048);
    _Float16* xe0 = (_Float16*)(smem + XE0_OFF);
    _Float16* xe1 = (_Float16*)(smem + XE1_OFF);

    const char*  CWF  = ws + WS_CW16;                      // fragment-ordered
    const half2* WB   = (const half2*)(ws + WS_WB16);      // [n][d] {w,b}
    const float* blog = (const float*)(ws + WS_BLOG);

    int bid = blockIdx.x;
    int b   = bid >> 1, ph = bid & 1;
    int tid = threadIdx.x;
    int w = tid >> 6, l = tid & 63, lq = l >> 4, lr = l & 15;
    int pt = w >> 1;                 // local p-tile 0..3
    int dh = w & 1;                  // d-half 0..1
    int p  = 64*ph + 16*pt + lr;     // this lane's prompt row (for logits/softmax)

    if (tid < 256) {
        x_s[tid]  = x[b*NCOLS + tid];
        g_s[tid]  = ln_emb_g[tid];
        bb_s[tid] = ln_emb_b[tid];
    }

    // prev row -> f16 B-fragments, held for all 4 chunks (32 VGPRs).
    // Wave pairs load identical rows (second hits L2/L1).
    half4 pfrag[16];
    {
        const float* prow = prev + ((size_t)b*NP + p)*DD + 4*lq;
        #pragma unroll
        for (int kc = 0; kc < 16; ++kc) {
            f32x4 v = *(const f32x4*)(prow + 16*kc);
            half4 h;
            #pragma unroll
            for (int j = 0; j < 4; ++j) h[j] = (_Float16)v[j];
            pfrag[kc] = h;
        }
    }
    __syncthreads();            // x_s ready

    // x_emb tile compute (64 n-rows) into transposed LDS [d][nloc], 8 rows/wave.
    // unroll 2: cap transient register pressure (8-way unroll was a spill driver).
    auto compute_xe = [&](int tile, _Float16* xb) {
        #pragma unroll 2
        for (int i = 0; i < 8; ++i) {
            int nloc = w + 8*i;
            int n = tile*64 + nloc;
            float xv = x_s[n];
            const half2* wbrow = WB + n*DD;
            float ev[4]; float s = 0.f, q = 0.f;
            #pragma unroll
            for (int c = 0; c < 4; ++c) {
                int d = l + 64*c;
                half2 pp = wbrow[d];
                float e = fmaf(xv, (float)pp[0], (float)pp[1]);
                e = e > 0.f ? e : 0.f;
                ev[c] = e; s += e; q += e*e;
            }
            #pragma unroll
            for (int off = 32; off; off >>= 1) { s += __shfl_xor(s, off); q += __shfl_xor(q, off); }
            float mu = s * (1.0f/DD);
            float rs = rsqrtf(q*(1.0f/DD) - mu*mu + 1e-5f);
            #pragma unroll
            for (int c = 0; c < 4; ++c) {
                int d = l + 64*c;
                xb[d*XE_STRIDE + nloc] = (_Float16)((ev[c]-mu)*rs*g_s[d] + bb_s[d]);
            }
        }
    };

    compute_xe(0, xe0);

    f32x4 acc_v[8];             // 16p x 128d quarter: d = 128*dh + 16*dt + 4lq + r
    #pragma unroll
    for (int dt = 0; dt < 8; ++dt) acc_v[dt] = (f32x4){0.f,0.f,0.f,0.f};
    float m = -1e30f, ll = 0.f;

    __syncthreads();            // xe0 ready

    const char*  cwlane = CWF + l*8;
    const float* blrow  = blog + (size_t)p*DD + 4*lq;

    for (int c = 0; c < 4; ++c) {
        _Float16* xcur = (c & 1) ? xe1 : xe0;
        _Float16* xnxt = (c & 1) ? xe0 : xe1;

        // ---- logits chunk: 16p x 64n, C-init from base_logits ----
        f32x4 acc_c[4];
        #pragma unroll
        for (int nt = 0; nt < 4; ++nt) acc_c[nt] = *(const f32x4*)(blrow + 64*c + 16*nt);
        #pragma unroll
        for (int kc = 0; kc < 16; ++kc) {
            const char* fb = cwlane + (size_t)(kc*16 + 4*c)*512;
            half4 a0 = *(const half4*)(fb);
            half4 a1 = *(const half4*)(fb + 512);
            half4 a2 = *(const half4*)(fb + 1024);
            half4 a3 = *(const half4*)(fb + 1536);
            half4 bp = pfrag[kc];
            acc_c[0] = MFMA16(a0, bp, acc_c[0]);
            acc_c[1] = MFMA16(a1, bp, acc_c[1]);
            acc_c[2] = MFMA16(a2, bp, acc_c[2]);
            acc_c[3] = MFMA16(a3, bp, acc_c[3]);
        }

        // ---- online softmax update (row p lane-local across lq: 2 shfls) ----
        float pmax = -1e30f;
        #pragma unroll
        for (int nt = 0; nt < 4; ++nt)
            #pragma unroll
            for (int r = 0; r < 4; ++r) pmax = fmaxf(pmax, acc_c[nt][r]);
        pmax = fmaxf(pmax, __shfl_xor(pmax, 16));
        pmax = fmaxf(pmax, __shfl_xor(pmax, 32));
        float mnew = fmaxf(m, pmax);
        float f = __expf(m - mnew);      // 0 on first chunk, 1 if max unchanged
        m = mnew;
        ll *= f;
        #pragma unroll
        for (int dt = 0; dt < 8; ++dt)
            #pragma unroll
            for (int r = 0; r < 4; ++r) acc_v[dt][r] *= f;

        float csum = 0.f;
        half4 p16c[4];
        #pragma unroll
        for (int nt = 0; nt < 4; ++nt) {
            half4 h;
            #pragma unroll
            for (int r = 0; r < 4; ++r) {
                float e = __expf(acc_c[nt][r] - m);
                csum += e;
                h[r] = (_Float16)e;
            }
            p16c[nt] = h;
        }
        csum += __shfl_xor(csum, 16);
        csum += __shfl_xor(csum, 32);
        ll += csum;

        // overlap next xe tile compute with this chunk's PV issue window
        if (c < 3) compute_xe(c+1, xnxt);

        // ---- PV: acc_v += xe_chunk^T @ P_chunk (this wave's 128-d half) ----
        #pragma unroll
        for (int kc2 = 0; kc2 < 4; ++kc2) {
            half4 bp = p16c[kc2];
            #pragma unroll
            for (int dt = 0; dt < 8; ++dt) {
                half4 a = *(const half4*)(xcur + (16*(8*dh + dt) + lr)*XE_STRIDE + kc2*16 + lq*4);
                acc_v[dt] = MFMA16(a, bp, acc_v[dt]);
            }
        }
        __syncthreads();
    }

    // epilogue: out = (V/ll)*sw + sb; col = p (lane lr), rows d = 128dh+16dt+4lq+r
    {
        float sw = (1.0f + expand_w[p]) / ll;
        float sb = expand_b[p];
        float* orow = out + ((size_t)b*NP + p)*DD + 128*dh + 4*lq;
        #pragma unroll
        for (int dt = 0; dt < 8; ++dt) {
            f32x4 v = acc_v[dt];
            #pragma unroll
            for (int r = 0; r < 4; ++r) v[r] = v[r]*sw + sb;
            *(f32x4*)(orow + 16*dt) = v;
        }
    }
}

// ============================ launcher ============================
extern "C" void kernel_launch(void* const* d_in, const int* in_sizes, int n_in,
                              void* d_out, int out_size, void* d_ws, size_t ws_size,
                              hipStream_t stream) {
    (void)in_sizes; (void)n_in; (void)out_size; (void)ws_size;
    const float* x           = (const float*)d_in[0];
    const float* prev        = (const float*)d_in[1];
    const float* few         = (const float*)d_in[2];
    const float* feb         = (const float*)d_in[3];
    const float* ln_emb_g    = (const float*)d_in[4];
    const float* ln_emb_b    = (const float*)d_in[5];
    const float* ln_col_g    = (const float*)d_in[6];
    const float* ln_col_b    = (const float*)d_in[7];
    const float* ln_prompt_g = (const float*)d_in[8];
    const float* ln_prompt_b = (const float*)d_in[9];
    const float* diw         = (const float*)d_in[10];
    const float* dib         = (const float*)d_in[11];
    const float* emb_column  = (const float*)d_in[12];
    const float* emb_prompt  = (const float*)d_in[13];
    const float* expand_w    = (const float*)d_in[14];
    const float* expand_b    = (const float*)d_in[15];
    char* ws = (char*)d_ws;
    float* out = (float*)d_out;

    k0a<<<512, 256, 0, stream>>>(emb_column, emb_prompt, ln_col_g, ln_col_b,
                                 ln_prompt_g, ln_prompt_b, few, feb, ws);
    k0b<<<384, 256, 0, stream>>>(diw, dib, emb_prompt, ws);
    k0c<<<128, 256, 0, stream>>>(ws);

    (void)hipFuncSetAttribute(reinterpret_cast<const void*>(trompt_main),
                              hipFuncAttributeMaxDynamicSharedMemorySize, SMEM_BYTES);
    trompt_main<<<2048, 512, SMEM_BYTES, stream>>>(x, prev, expand_w, expand_b,
                                                   ln_emb_g, ln_emb_b, ws, out);
}

// Round 8
// 363.562 us; speedup vs baseline: 1.0235x; 1.0235x over previous
//
#include <hip/hip_runtime.h>

#define NCOLS 256
#define NP    128
#define DD    256

typedef _Float16 half4 __attribute__((ext_vector_type(4)));
typedef float    f32x4 __attribute__((ext_vector_type(4)));

// gfx950 spelling has no underscore before f16 (compiler-confirmed)
#define MFMA16(a,b,c) __builtin_amdgcn_mfma_f32_16x16x16f16(a,b,c,0,0,0)

// ---- workspace layout (bytes) ----
#define WS_COL_LN   0          // f32 [256][256]  LN(emb_column)
#define WS_LNP      262144     // f32 [128][256]  LN(emb_prompt)
#define WS_BASE     393216     // f32 [128][256]  base (prompt-side xp part)
#define WS_BLOG     524288     // f32 [128][256]  base_logits
#define WS_CW16     655360     // f16 CW in MFMA A-fragment order (see k0b)

// main LDS: prev as f16 [128 p][256 k], XOR-swizzled, 64 KB
#define SMEM_MAIN 65536

// ============================ stage 0 kernels ============================

// blocks 0..255: LN rows of emb_column; 256..383: LN rows of emb_prompt
__global__ __launch_bounds__(256) void k0a(
    const float* __restrict__ emb_column, const float* __restrict__ emb_prompt,
    const float* __restrict__ ln_col_g, const float* __restrict__ ln_col_b,
    const float* __restrict__ ln_prompt_g, const float* __restrict__ ln_prompt_b,
    char* __restrict__ ws)
{
    __shared__ float red[10];
    int blk = blockIdx.x, tid = threadIdx.x;
    const float *src, *g, *bb; float* dst;
    if (blk < 256) { int r = blk;     src = emb_column + r*DD; g = ln_col_g;    bb = ln_col_b;    dst = (float*)(ws + WS_COL_LN) + r*DD; }
    else           { int r = blk-256; src = emb_prompt + r*DD; g = ln_prompt_g; bb = ln_prompt_b; dst = (float*)(ws + WS_LNP) + r*DD; }
    float v = src[tid];
    float s = v, q = v*v;
    #pragma unroll
    for (int off = 32; off; off >>= 1) { s += __shfl_xor(s, off); q += __shfl_xor(q, off); }
    int wid = tid >> 6, lane = tid & 63;
    if (lane == 0) { red[wid] = s; red[4+wid] = q; }
    __syncthreads();
    if (tid == 0) {
        float S = red[0]+red[1]+red[2]+red[3];
        float Q = red[4]+red[5]+red[6]+red[7];
        float mu = S * (1.0f/DD);
        float var = Q * (1.0f/DD) - mu*mu;
        red[8] = mu; red[9] = rsqrtf(var + 1e-5f);
    }
    __syncthreads();
    dst[tid] = (v - red[8]) * red[9] * g[tid] + bb[tid];
}

// blocks 0..255: CW[n][k] = sum_d col_ln[n][d] * diw[d][256+k], stored in
//   MFMA A-fragment order: f16 index ((kc*16+nt)*64 + lq*16 + lr)*4 + j
//   with n = 16nt+lr, k = 16kc+4lq+j.
// blocks 256..383: base[p][d] = sum_k LNp[p][k]*diw[d][k] + dib[d] + emb_prompt[p][d]
__global__ __launch_bounds__(256) void k0b(
    const float* __restrict__ diw, const float* __restrict__ dib,
    const float* __restrict__ emb_prompt, char* __restrict__ ws)
{
    __shared__ float rowv[DD];
    int blk = blockIdx.x, tid = threadIdx.x;
    if (blk < 256) {
        int n = blk;
        const float* col_ln = (const float*)(ws + WS_COL_LN);
        rowv[tid] = col_ln[n*DD + tid];
        __syncthreads();
        float acc = 0.f;
        #pragma unroll 4
        for (int d = 0; d < DD; ++d) acc += rowv[d] * diw[d*512 + 256 + tid];
        int nt = n >> 4, lr = n & 15;
        int kc = tid >> 4, lq = (tid >> 2) & 3, j = tid & 3;
        ((_Float16*)(ws + WS_CW16))[((kc*16 + nt)*64 + lq*16 + lr)*4 + j] = (_Float16)acc;
    } else {
        int p = blk - 256;
        const float* lnp = (const float*)(ws + WS_LNP);
        rowv[tid] = lnp[p*DD + tid];
        __syncthreads();
        float acc = 0.f;
        #pragma unroll 4
        for (int k = 0; k < DD; ++k) acc += rowv[k] * diw[tid*512 + k];
        ((float*)(ws + WS_BASE))[p*DD + tid] = acc + dib[tid] + emb_prompt[p*DD + tid];
    }
}

// base_logits[p][n] = sum_d base[p][d] * col_ln[n][d]
__global__ __launch_bounds__(256) void k0c(char* __restrict__ ws)
{
    __shared__ float bs[DD];
    int p = blockIdx.x, n = threadIdx.x;
    const float* base   = (const float*)(ws + WS_BASE);
    const float* col_ln = (const float*)(ws + WS_COL_LN);
    bs[n] = base[p*DD + n];
    __syncthreads();
    float acc = 0.f;
    #pragma unroll 4
    for (int d = 0; d < DD; ++d) acc += bs[d] * col_ln[n*DD + d];
    ((float*)(ws + WS_BLOG))[p*DD + n] = acc;
}

// ============================ x_emb kernel ============================
// 1 block = 1 batch (grid 1024, 256 thr, 4 waves). Computes
// x_emb[n][d] = LN(relu(x[n]*W[n][d]+B[n][d])) and stores f16 in PV
// A-fragment order into xef (aliased onto d_out):
//   flat = (((c*4+kc2)*16 + dt)*64 + lq*16 + lr)*4 + j
//   with n = 64c+16kc2+4lq+j, d = 16dt+lr.
// Wave processes groups of 4 consecutive n (same c,kc2,lq; j=0..3).
__global__ __launch_bounds__(256) void k_xe(
    const float* __restrict__ x, const float* __restrict__ few,
    const float* __restrict__ feb, const float* __restrict__ ln_emb_g,
    const float* __restrict__ ln_emb_b, _Float16* xef)
{
    __shared__ float x_s[256], g_s[256], b_s[256];
    int b = blockIdx.x, tid = threadIdx.x, w = tid >> 6, l = tid & 63;
    x_s[tid] = x[b*NCOLS + tid];
    g_s[tid] = ln_emb_g[tid];
    b_s[tid] = ln_emb_b[tid];
    __syncthreads();

    _Float16* xb = xef + (size_t)b*65536;
    for (int gi = 0; gi < 16; ++gi) {
        int g = w + 4*gi;                 // group 0..63
        int c = g >> 4, kc2 = (g >> 2) & 3, lq = g & 3;
        float vj[4][4];                   // [j][cc]
        #pragma unroll
        for (int j = 0; j < 4; ++j) {
            int n = 4*g + j;
            float xv = x_s[n];
            float s = 0.f, q = 0.f;
            #pragma unroll
            for (int cc = 0; cc < 4; ++cc) {
                int d = l + 64*cc;
                float e = fmaf(xv, few[n*DD + d], feb[n*DD + d]);
                e = e > 0.f ? e : 0.f;
                vj[j][cc] = e; s += e; q += e*e;
            }
            #pragma unroll
            for (int off = 32; off; off >>= 1) { s += __shfl_xor(s, off); q += __shfl_xor(q, off); }
            float mu = s * (1.0f/DD);
            float rs = rsqrtf(q*(1.0f/DD) - mu*mu + 1e-5f);
            #pragma unroll
            for (int cc = 0; cc < 4; ++cc) {
                int d = l + 64*cc;
                vj[j][cc] = (vj[j][cc]-mu)*rs*g_s[d] + b_s[d];
            }
        }
        #pragma unroll
        for (int cc = 0; cc < 4; ++cc) {
            int dt = 4*cc + (l >> 4), lr = l & 15;
            half4 h;
            #pragma unroll
            for (int j = 0; j < 4; ++j) h[j] = (_Float16)vj[j][cc];
            *(half4*)(xb + ((((c*4 + kc2)*16 + dt)*64) + lq*16 + lr)*4) = h;
        }
    }
}

// ============================ main kernel ============================
// 1 block = 1 batch (grid 1024, 512 thr, 8 waves). Wave w owns p-rows
// [16w,16w+16) x all 256 d. prev staged once to XOR-swizzled f16 LDS.
// Flash loop over 4 n-chunks of 64: logits (A=CW frags from L2,
// B=prev frags from LDS, C-init=blog) -> online softmax -> PV
// (A=xe frags from global, B=P in-reg). Barrier-free inner loop.
__global__ __launch_bounds__(512, 4) void trompt_main(
    const float* __restrict__ prev,
    const float* __restrict__ expand_w, const float* __restrict__ expand_b,
    const char* __restrict__ ws, const _Float16* xef, float* out)
{
    extern __shared__ char smem[];      // prev f16 [128][256], swizzled

    int b = blockIdx.x;
    int tid = threadIdx.x;
    int w = tid >> 6, l = tid & 63, lq = l >> 4, lr = l & 15;

    // ---- stage prev -> f16 LDS, byte kb ^= (p&7)<<4 within each row ----
    {
        const f32x4* src = (const f32x4*)(prev + (size_t)b*NP*DD);
        #pragma unroll 4
        for (int i = 0; i < 16; ++i) {
            int idx = tid + 512*i;          // f32x4 index; 64 per p-row
            f32x4 v = src[idx];
            half4 h;
            #pragma unroll
            for (int j = 0; j < 4; ++j) h[j] = (_Float16)v[j];
            int p = idx >> 6;
            int kb = (idx & 63) * 8;
            *(half4*)(smem + p*512 + (kb ^ ((p & 7) << 4))) = h;
        }
    }
    __syncthreads();

    int p = 16*w + lr;
    const char*  cwlane = ws + WS_CW16 + l*8;
    const float* blrow  = (const float*)(ws + WS_BLOG) + (size_t)p*DD + 4*lq;
    const char*  xfl    = (const char*)(xef + (size_t)b*65536) + l*8;
    const char*  prow   = smem + p*512;
    int pxor = (p & 7) << 4;

    f32x4 acc_v[16];
    #pragma unroll
    for (int dt = 0; dt < 16; ++dt) acc_v[dt] = (f32x4){0.f,0.f,0.f,0.f};
    float m = -1e30f, ll = 0.f;

    for (int c = 0; c < 4; ++c) {
        // ---- logits chunk: 16p x 64n ----
        f32x4 acc_c[4];
        #pragma unroll
        for (int nt = 0; nt < 4; ++nt) acc_c[nt] = *(const f32x4*)(blrow + 64*c + 16*nt);
        #pragma unroll
        for (int kc = 0; kc < 16; ++kc) {
            half4 bp = *(const half4*)(prow + ((32*kc + 8*lq) ^ pxor));
            const char* fb = cwlane + (size_t)(kc*16 + 4*c)*512;
            half4 a0 = *(const half4*)(fb);
            half4 a1 = *(const half4*)(fb + 512);
            half4 a2 = *(const half4*)(fb + 1024);
            half4 a3 = *(const half4*)(fb + 1536);
            acc_c[0] = MFMA16(a0, bp, acc_c[0]);
            acc_c[1] = MFMA16(a1, bp, acc_c[1]);
            acc_c[2] = MFMA16(a2, bp, acc_c[2]);
            acc_c[3] = MFMA16(a3, bp, acc_c[3]);
        }

        // ---- online softmax update (p lane-local across lq: 2 shfls) ----
        float pmax = -1e30f;
        #pragma unroll
        for (int nt = 0; nt < 4; ++nt)
            #pragma unroll
            for (int r = 0; r < 4; ++r) pmax = fmaxf(pmax, acc_c[nt][r]);
        pmax = fmaxf(pmax, __shfl_xor(pmax, 16));
        pmax = fmaxf(pmax, __shfl_xor(pmax, 32));
        float mnew = fmaxf(m, pmax);
        float f = __expf(m - mnew);
        m = mnew;
        ll *= f;
        #pragma unroll
        for (int dt = 0; dt < 16; ++dt)
            #pragma unroll
            for (int r = 0; r < 4; ++r) acc_v[dt][r] *= f;

        float csum = 0.f;
        half4 p16c[4];
        #pragma unroll
        for (int nt = 0; nt < 4; ++nt) {
            half4 h;
            #pragma unroll
            for (int r = 0; r < 4; ++r) {
                float e = __expf(acc_c[nt][r] - m);
                csum += e;
                h[r] = (_Float16)e;
            }
            p16c[nt] = h;
        }
        csum += __shfl_xor(csum, 16);
        csum += __shfl_xor(csum, 32);
        ll += csum;

        // ---- PV: acc_v += xe_chunk^T @ P_chunk (A-frags from global) ----
        #pragma unroll
        for (int kc2 = 0; kc2 < 4; ++kc2) {
            half4 bp = p16c[kc2];
            #pragma unroll
            for (int dt = 0; dt < 16; ++dt) {
                half4 a = *(const half4*)(xfl + (size_t)((c*4 + kc2)*16 + dt)*512);
                acc_v[dt] = MFMA16(a, bp, acc_v[dt]);
            }
        }
    }

    // all xe reads (aliased with out) must complete before stores
    __syncthreads();

    // epilogue: out = (V/ll)*sw + sb; col p = lane lr, rows d = 16dt+4lq+r
    {
        float sw = (1.0f + expand_w[p]) / ll;
        float sb = expand_b[p];
        float* orow = out + ((size_t)b*NP + p)*DD + 4*lq;
        #pragma unroll
        for (int dt = 0; dt < 16; ++dt) {
            f32x4 v = acc_v[dt];
            #pragma unroll
            for (int r = 0; r < 4; ++r) v[r] = v[r]*sw + sb;
            *(f32x4*)(orow + 16*dt) = v;
        }
    }
}

// ============================ launcher ============================
extern "C" void kernel_launch(void* const* d_in, const int* in_sizes, int n_in,
                              void* d_out, int out_size, void* d_ws, size_t ws_size,
                              hipStream_t stream) {
    (void)in_sizes; (void)n_in; (void)out_size; (void)ws_size;
    const float* x           = (const float*)d_in[0];
    const float* prev        = (const float*)d_in[1];
    const float* few         = (const float*)d_in[2];
    const float* feb         = (const float*)d_in[3];
    const float* ln_emb_g    = (const float*)d_in[4];
    const float* ln_emb_b    = (const float*)d_in[5];
    const float* ln_col_g    = (const float*)d_in[6];
    const float* ln_col_b    = (const float*)d_in[7];
    const float* ln_prompt_g = (const float*)d_in[8];
    const float* ln_prompt_b = (const float*)d_in[9];
    const float* diw         = (const float*)d_in[10];
    const float* dib         = (const float*)d_in[11];
    const float* emb_column  = (const float*)d_in[12];
    const float* emb_prompt  = (const float*)d_in[13];
    const float* expand_w    = (const float*)d_in[14];
    const float* expand_b    = (const float*)d_in[15];
    char* ws = (char*)d_ws;
    float* out = (float*)d_out;
    _Float16* xef = (_Float16*)d_out;   // xe[b] occupies exactly out[b]'s 128 KB

    k0a<<<384, 256, 0, stream>>>(emb_column, emb_prompt, ln_col_g, ln_col_b,
                                 ln_prompt_g, ln_prompt_b, ws);
    k0b<<<384, 256, 0, stream>>>(diw, dib, emb_prompt, ws);
    k0c<<<128, 256, 0, stream>>>(ws);
    k_xe<<<1024, 256, 0, stream>>>(x, few, feb, ln_emb_g, ln_emb_b, xef);

    (void)hipFuncSetAttribute(reinterpret_cast<const void*>(trompt_main),
                              hipFuncAttributeMaxDynamicSharedMemorySize, SMEM_MAIN);
    trompt_main<<<1024, 512, SMEM_MAIN, stream>>>(prev, expand_w, expand_b,
                                                  ws, xef, out);
}

// Round 9
// 234.992 us; speedup vs baseline: 1.5835x; 1.5471x over previous
//
#include <hip/hip_runtime.h>

#define NCOLS 256
#define NP    128
#define DD    256

typedef _Float16 half4 __attribute__((ext_vector_type(4)));
typedef float    f32x4 __attribute__((ext_vector_type(4)));

// gfx950 spelling has no underscore before f16 (compiler-confirmed)
#define MFMA16(a,b,c) __builtin_amdgcn_mfma_f32_16x16x16f16(a,b,c,0,0,0)

// ---- workspace layout (bytes) ----
#define WS_COL_LN   0          // f32 [256][256]  LN(emb_column)
#define WS_LNP      262144     // f32 [128][256]  LN(emb_prompt)
#define WS_BASE     393216     // f32 [128][256]  base (prompt-side xp part)
#define WS_BLOG     524288     // f32 [128][256]  base_logits
#define WS_CW16     655360     // f16 CW in MFMA A-fragment order (see k0b)

// main LDS: one chunk's A-operands: CW slice 32 KB @0, xe slice 32 KB @32768
#define SMEM_MAIN 65536        // 2 blocks/CU (131072 <= 163840)

// ============================ stage 0 kernels ============================

// blocks 0..255: LN rows of emb_column; 256..383: LN rows of emb_prompt
__global__ __launch_bounds__(256) void k0a(
    const float* __restrict__ emb_column, const float* __restrict__ emb_prompt,
    const float* __restrict__ ln_col_g, const float* __restrict__ ln_col_b,
    const float* __restrict__ ln_prompt_g, const float* __restrict__ ln_prompt_b,
    char* __restrict__ ws)
{
    __shared__ float red[10];
    int blk = blockIdx.x, tid = threadIdx.x;
    const float *src, *g, *bb; float* dst;
    if (blk < 256) { int r = blk;     src = emb_column + r*DD; g = ln_col_g;    bb = ln_col_b;    dst = (float*)(ws + WS_COL_LN) + r*DD; }
    else           { int r = blk-256; src = emb_prompt + r*DD; g = ln_prompt_g; bb = ln_prompt_b; dst = (float*)(ws + WS_LNP) + r*DD; }
    float v = src[tid];
    float s = v, q = v*v;
    #pragma unroll
    for (int off = 32; off; off >>= 1) { s += __shfl_xor(s, off); q += __shfl_xor(q, off); }
    int wid = tid >> 6, lane = tid & 63;
    if (lane == 0) { red[wid] = s; red[4+wid] = q; }
    __syncthreads();
    if (tid == 0) {
        float S = red[0]+red[1]+red[2]+red[3];
        float Q = red[4]+red[5]+red[6]+red[7];
        float mu = S * (1.0f/DD);
        float var = Q * (1.0f/DD) - mu*mu;
        red[8] = mu; red[9] = rsqrtf(var + 1e-5f);
    }
    __syncthreads();
    dst[tid] = (v - red[8]) * red[9] * g[tid] + bb[tid];
}

// blocks 0..255: CW[n][k] = sum_d col_ln[n][d] * diw[d][256+k], stored in
//   MFMA A-fragment order: f16 index ((kc*16+nt)*64 + lq*16 + lr)*4 + j
//   with n = 16nt+lr, k = 16kc+4lq+j.
// blocks 256..383: base[p][d] = sum_k LNp[p][k]*diw[d][k] + dib[d] + emb_prompt[p][d]
__global__ __launch_bounds__(256) void k0b(
    const float* __restrict__ diw, const float* __restrict__ dib,
    const float* __restrict__ emb_prompt, char* __restrict__ ws)
{
    __shared__ float rowv[DD];
    int blk = blockIdx.x, tid = threadIdx.x;
    if (blk < 256) {
        int n = blk;
        const float* col_ln = (const float*)(ws + WS_COL_LN);
        rowv[tid] = col_ln[n*DD + tid];
        __syncthreads();
        float acc = 0.f;
        #pragma unroll 4
        for (int d = 0; d < DD; ++d) acc += rowv[d] * diw[d*512 + 256 + tid];
        int nt = n >> 4, lr = n & 15;
        int kc = tid >> 4, lq = (tid >> 2) & 3, j = tid & 3;
        ((_Float16*)(ws + WS_CW16))[((kc*16 + nt)*64 + lq*16 + lr)*4 + j] = (_Float16)acc;
    } else {
        int p = blk - 256;
        const float* lnp = (const float*)(ws + WS_LNP);
        rowv[tid] = lnp[p*DD + tid];
        __syncthreads();
        float acc = 0.f;
        #pragma unroll 4
        for (int k = 0; k < DD; ++k) acc += rowv[k] * diw[tid*512 + k];
        ((float*)(ws + WS_BASE))[p*DD + tid] = acc + dib[tid] + emb_prompt[p*DD + tid];
    }
}

// base_logits[p][n] = sum_d base[p][d] * col_ln[n][d]
__global__ __launch_bounds__(256) void k0c(char* __restrict__ ws)
{
    __shared__ float bs[DD];
    int p = blockIdx.x, n = threadIdx.x;
    const float* base   = (const float*)(ws + WS_BASE);
    const float* col_ln = (const float*)(ws + WS_COL_LN);
    bs[n] = base[p*DD + n];
    __syncthreads();
    float acc = 0.f;
    #pragma unroll 4
    for (int d = 0; d < DD; ++d) acc += bs[d] * col_ln[n*DD + d];
    ((float*)(ws + WS_BLOG))[p*DD + n] = acc;
}

// ============================ x_emb kernel ============================
// 1 block = 1 batch (grid 1024, 256 thr). x_emb in PV A-fragment order
// into xef (aliased onto d_out):
//   flat = (((c*4+kc2)*16 + dt)*64 + l)*4 f16,  n = 64c+16kc2+4lq+j, d = 16dt+lr.
__global__ __launch_bounds__(256) void k_xe(
    const float* __restrict__ x, const float* __restrict__ few,
    const float* __restrict__ feb, const float* __restrict__ ln_emb_g,
    const float* __restrict__ ln_emb_b, _Float16* xef)
{
    __shared__ float x_s[256], g_s[256], b_s[256];
    int b = blockIdx.x, tid = threadIdx.x, w = tid >> 6, l = tid & 63;
    x_s[tid] = x[b*NCOLS + tid];
    g_s[tid] = ln_emb_g[tid];
    b_s[tid] = ln_emb_b[tid];
    __syncthreads();

    _Float16* xb = xef + (size_t)b*65536;
    for (int gi = 0; gi < 16; ++gi) {
        int g = w + 4*gi;                 // group 0..63
        int c = g >> 4, kc2 = (g >> 2) & 3, lq = g & 3;
        float vj[4][4];                   // [j][cc]
        #pragma unroll
        for (int j = 0; j < 4; ++j) {
            int n = 4*g + j;
            float xv = x_s[n];
            float s = 0.f, q = 0.f;
            #pragma unroll
            for (int cc = 0; cc < 4; ++cc) {
                int d = l + 64*cc;
                float e = fmaf(xv, few[n*DD + d], feb[n*DD + d]);
                e = e > 0.f ? e : 0.f;
                vj[j][cc] = e; s += e; q += e*e;
            }
            #pragma unroll
            for (int off = 32; off; off >>= 1) { s += __shfl_xor(s, off); q += __shfl_xor(q, off); }
            float mu = s * (1.0f/DD);
            float rs = rsqrtf(q*(1.0f/DD) - mu*mu + 1e-5f);
            #pragma unroll
            for (int cc = 0; cc < 4; ++cc) {
                int d = l + 64*cc;
                vj[j][cc] = (vj[j][cc]-mu)*rs*g_s[d] + b_s[d];
            }
        }
        #pragma unroll
        for (int cc = 0; cc < 4; ++cc) {
            int dt = 4*cc + (l >> 4), lr = l & 15;
            half4 h;
            #pragma unroll
            for (int j = 0; j < 4; ++j) h[j] = (_Float16)vj[j][cc];
            *(half4*)(xb + ((((c*4 + kc2)*16 + dt)*64) + lq*16 + lr)*4) = h;
        }
    }
}

// ============================ main kernel ============================
// 1 block = 1 batch (grid 1024, 512 thr, 8 waves). Wave w owns p-rows
// [16w,16w+16) x all 256 d. Flash loop over 4 n-chunks of 64.
// Per chunk, the A-operands (CW slice 32 KB + xe slice 32 KB) are staged
// ONCE into LDS and shared by all 8 waves; MFMA reads are ds_read_b64.
// B-operands (prev f16 frags) and P live in registers. No per-wave global
// streaming in the inner loop.
__global__ __launch_bounds__(512, 4) void trompt_main(
    const float* __restrict__ prev,
    const float* __restrict__ expand_w, const float* __restrict__ expand_b,
    const char* __restrict__ ws, const _Float16* xef, float* out)
{
    extern __shared__ char smem[];      // [0,32K): CW slice  [32K,64K): xe slice

    int b = blockIdx.x;
    int tid = threadIdx.x;
    int w = tid >> 6, l = tid & 63, lq = l >> 4, lr = l & 15;
    int p = 16*w + lr;

    const char* cwbase = ws + WS_CW16;
    const char* xebase = (const char*)(xef + (size_t)b*65536);

    // cooperative chunk staging: 128 B/thread, 16B coalesced pieces.
    // CW slice: frag (kc*16 + 4c + nt) -> lds kc*2048 + nt*512 + lane*8
    // xe slice: frag ((c*4+kc2)*16 + dt) -> lds 32768 + kc2*8192 + dt*512 + lane*8
    auto stage = [&](int c) {
        #pragma unroll
        for (int i = 0; i < 4; ++i) {
            int u = tid + 512*i;                  // 0..2047
            int kc = u >> 7, rem = u & 127;
            uint4 v = *(const uint4*)(cwbase + kc*8192 + c*2048 + rem*16);
            *(uint4*)(smem + u*16) = v;
        }
        #pragma unroll
        for (int i = 0; i < 4; ++i) {
            int u = tid + 512*i;                  // 0..2047
            int kc2 = u >> 9, rem = u & 511;
            uint4 v = *(const uint4*)(xebase + c*32768 + kc2*8192 + rem*16);
            *(uint4*)(smem + 32768 + u*16) = v;
        }
    };

    stage(0);

    // prev row -> f16 B-fragments (32 VGPRs), live across all chunks
    half4 pfrag[16];
    {
        const float* prow = prev + ((size_t)b*NP + p)*DD + 4*lq;
        #pragma unroll
        for (int kc = 0; kc < 16; ++kc) {
            f32x4 v = *(const f32x4*)(prow + 16*kc);
            half4 h;
            #pragma unroll
            for (int j = 0; j < 4; ++j) h[j] = (_Float16)v[j];
            pfrag[kc] = h;
        }
    }

    f32x4 acc_v[16];
    #pragma unroll
    for (int dt = 0; dt < 16; ++dt) acc_v[dt] = (f32x4){0.f,0.f,0.f,0.f};
    float m = -1e30f, ll = 0.f;

    const float* blrow = (const float*)(ws + WS_BLOG) + (size_t)p*DD + 4*lq;
    const char*  cwl   = smem + l*8;
    const char*  xel   = smem + 32768 + l*8;

    __syncthreads();                    // chunk 0 staged

    for (int c = 0; c < 4; ++c) {
        // ---- logits chunk: 16p x 64n, C-init from base_logits ----
        f32x4 acc_c[4];
        #pragma unroll
        for (int nt = 0; nt < 4; ++nt) acc_c[nt] = *(const f32x4*)(blrow + 64*c + 16*nt);
        #pragma unroll
        for (int kc = 0; kc < 16; ++kc) {
            const char* fb = cwl + kc*2048;
            half4 a0 = *(const half4*)(fb);
            half4 a1 = *(const half4*)(fb + 512);
            half4 a2 = *(const half4*)(fb + 1024);
            half4 a3 = *(const half4*)(fb + 1536);
            half4 bp = pfrag[kc];
            acc_c[0] = MFMA16(a0, bp, acc_c[0]);
            acc_c[1] = MFMA16(a1, bp, acc_c[1]);
            acc_c[2] = MFMA16(a2, bp, acc_c[2]);
            acc_c[3] = MFMA16(a3, bp, acc_c[3]);
        }

        // ---- online softmax update (p lane-local across lq: 2 shfls) ----
        float pmax = -1e30f;
        #pragma unroll
        for (int nt = 0; nt < 4; ++nt)
            #pragma unroll
            for (int r = 0; r < 4; ++r) pmax = fmaxf(pmax, acc_c[nt][r]);
        pmax = fmaxf(pmax, __shfl_xor(pmax, 16));
        pmax = fmaxf(pmax, __shfl_xor(pmax, 32));
        float mnew = fmaxf(m, pmax);
        float f = __expf(m - mnew);
        m = mnew;
        ll *= f;
        #pragma unroll
        for (int dt = 0; dt < 16; ++dt)
            #pragma unroll
            for (int r = 0; r < 4; ++r) acc_v[dt][r] *= f;

        float csum = 0.f;
        half4 p16c[4];
        #pragma unroll
        for (int nt = 0; nt < 4; ++nt) {
            half4 h;
            #pragma unroll
            for (int r = 0; r < 4; ++r) {
                float e = __expf(acc_c[nt][r] - m);
                csum += e;
                h[r] = (_Float16)e;
            }
            p16c[nt] = h;
        }
        csum += __shfl_xor(csum, 16);
        csum += __shfl_xor(csum, 32);
        ll += csum;

        // ---- PV: acc_v += xe_chunk^T @ P_chunk (A-frags from LDS) ----
        #pragma unroll
        for (int kc2 = 0; kc2 < 4; ++kc2) {
            half4 bp = p16c[kc2];
            const char* xb = xel + kc2*8192;
            #pragma unroll
            for (int dt = 0; dt < 16; ++dt) {
                half4 a = *(const half4*)(xb + dt*512);
                acc_v[dt] = MFMA16(a, bp, acc_v[dt]);
            }
        }

        if (c < 3) {
            __syncthreads();            // all waves done reading buf
            stage(c+1);
            __syncthreads();            // next chunk ready
        }
    }

    // epilogue: out = (V/ll)*sw + sb; col p = lane lr, rows d = 16dt+4lq+r
    // (all global xe reads finished at the last staging barrier -> safe to
    //  overwrite out[b], which aliases xef[b]; only this block touches b)
    {
        float sw = (1.0f + expand_w[p]) / ll;
        float sb = expand_b[p];
        float* orow = out + ((size_t)b*NP + p)*DD + 4*lq;
        #pragma unroll
        for (int dt = 0; dt < 16; ++dt) {
            f32x4 v = acc_v[dt];
            #pragma unroll
            for (int r = 0; r < 4; ++r) v[r] = v[r]*sw + sb;
            *(f32x4*)(orow + 16*dt) = v;
        }
    }
}

// ============================ launcher ============================
extern "C" void kernel_launch(void* const* d_in, const int* in_sizes, int n_in,
                              void* d_out, int out_size, void* d_ws, size_t ws_size,
                              hipStream_t stream) {
    (void)in_sizes; (void)n_in; (void)out_size; (void)ws_size;
    const float* x           = (const float*)d_in[0];
    const float* prev        = (const float*)d_in[1];
    const float* few         = (const float*)d_in[2];
    const float* feb         = (const float*)d_in[3];
    const float* ln_emb_g    = (const float*)d_in[4];
    const float* ln_emb_b    = (const float*)d_in[5];
    const float* ln_col_g    = (const float*)d_in[6];
    const float* ln_col_b    = (const float*)d_in[7];
    const float* ln_prompt_g = (const float*)d_in[8];
    const float* ln_prompt_b = (const float*)d_in[9];
    const float* diw         = (const float*)d_in[10];
    const float* dib         = (const float*)d_in[11];
    const float* emb_column  = (const float*)d_in[12];
    const float* emb_prompt  = (const float*)d_in[13];
    const float* expand_w    = (const float*)d_in[14];
    const float* expand_b    = (const float*)d_in[15];
    char* ws = (char*)d_ws;
    float* out = (float*)d_out;
    _Float16* xef = (_Float16*)d_out;   // xe[b] occupies exactly out[b]'s 128 KB

    k0a<<<384, 256, 0, stream>>>(emb_column, emb_prompt, ln_col_g, ln_col_b,
                                 ln_prompt_g, ln_prompt_b, ws);
    k0b<<<384, 256, 0, stream>>>(diw, dib, emb_prompt, ws);
    k0c<<<128, 256, 0, stream>>>(ws);
    k_xe<<<1024, 256, 0, stream>>>(x, few, feb, ln_emb_g, ln_emb_b, xef);

    (void)hipFuncSetAttribute(reinterpret_cast<const void*>(trompt_main),
                              hipFuncAttributeMaxDynamicSharedMemorySize, SMEM_MAIN);
    trompt_main<<<1024, 512, SMEM_MAIN, stream>>>(prev, expand_w, expand_b,
                                                  ws, xef, out);
}

// Round 10
// 201.995 us; speedup vs baseline: 1.8422x; 1.1634x over previous
//
#include <hip/hip_runtime.h>

#define NCOLS 256
#define NP    128
#define DD    256

typedef _Float16 half2 __attribute__((ext_vector_type(2)));
typedef _Float16 half4 __attribute__((ext_vector_type(4)));
typedef float    f32x4 __attribute__((ext_vector_type(4)));

// gfx950 spelling has no underscore before f16 (compiler-confirmed)
#define MFMA16(a,b,c) __builtin_amdgcn_mfma_f32_16x16x16f16(a,b,c,0,0,0)

// ---- workspace layout (bytes) ----
#define WS_COL_LN   0          // f32 [256][256]  LN(emb_column)
#define WS_LNP      262144     // f32 [128][256]  LN(emb_prompt)
#define WS_BASE     393216     // f32 [128][256]  base (prompt-side xp part)
#define WS_BLOG     524288     // f32 [128][256]  base_logits
#define WS_CW16     655360     // f16 CW in MFMA A-fragment order (see k0b)
#define WS_WB16     786432     // half2 [256][256] {w,b} interleaved feature emb

// ---- main LDS layout (bytes): x/g/b vectors + double-buffered chunk ----
// buf c&1: CW slice 32 KB + xe slice 32 KB
#define LDS_CW0   3072
#define LDS_XE0   35840
#define LDS_CW1   68608
#define LDS_XE1   101376
#define SMEM_MAIN 134144       // 1 block/CU

// ============================ stage 0 kernels ============================

// blocks 0..255: LN rows of emb_column; 256..383: LN rows of emb_prompt;
// 384..511: half2 {w,b} interleave of feature emb weights.
__global__ __launch_bounds__(256) void k0a(
    const float* __restrict__ emb_column, const float* __restrict__ emb_prompt,
    const float* __restrict__ ln_col_g, const float* __restrict__ ln_col_b,
    const float* __restrict__ ln_prompt_g, const float* __restrict__ ln_prompt_b,
    const float* __restrict__ few, const float* __restrict__ feb,
    char* __restrict__ ws)
{
    __shared__ float red[10];
    int blk = blockIdx.x, tid = threadIdx.x;
    if (blk < 384) {
        const float *src, *g, *bb; float* dst;
        if (blk < 256) { int r = blk;     src = emb_column + r*DD; g = ln_col_g;    bb = ln_col_b;    dst = (float*)(ws + WS_COL_LN) + r*DD; }
        else           { int r = blk-256; src = emb_prompt + r*DD; g = ln_prompt_g; bb = ln_prompt_b; dst = (float*)(ws + WS_LNP) + r*DD; }
        float v = src[tid];
        float s = v, q = v*v;
        #pragma unroll
        for (int off = 32; off; off >>= 1) { s += __shfl_xor(s, off); q += __shfl_xor(q, off); }
        int wid = tid >> 6, lane = tid & 63;
        if (lane == 0) { red[wid] = s; red[4+wid] = q; }
        __syncthreads();
        if (tid == 0) {
            float S = red[0]+red[1]+red[2]+red[3];
            float Q = red[4]+red[5]+red[6]+red[7];
            float mu = S * (1.0f/DD);
            float var = Q * (1.0f/DD) - mu*mu;
            red[8] = mu; red[9] = rsqrtf(var + 1e-5f);
        }
        __syncthreads();
        dst[tid] = (v - red[8]) * red[9] * g[tid] + bb[tid];
    } else {
        int base = (blk - 384) * 512;
        half2* wb = (half2*)(ws + WS_WB16);
        #pragma unroll
        for (int j = 0; j < 2; ++j) {
            int idx = base + j*256 + tid;      // 0..65535
            half2 h; h[0] = (_Float16)few[idx]; h[1] = (_Float16)feb[idx];
            wb[idx] = h;
        }
    }
}

// blocks 0..255: CW[n][k] = sum_d col_ln[n][d] * diw[d][256+k], stored in
//   MFMA A-fragment order: f16 index ((kc*16+nt)*64 + lq*16 + lr)*4 + j
//   with n = 16nt+lr, k = 16kc+4lq+j.
// blocks 256..383: base[p][d] = sum_k LNp[p][k]*diw[d][k] + dib[d] + emb_prompt[p][d]
__global__ __launch_bounds__(256) void k0b(
    const float* __restrict__ diw, const float* __restrict__ dib,
    const float* __restrict__ emb_prompt, char* __restrict__ ws)
{
    __shared__ float rowv[DD];
    int blk = blockIdx.x, tid = threadIdx.x;
    if (blk < 256) {
        int n = blk;
        const float* col_ln = (const float*)(ws + WS_COL_LN);
        rowv[tid] = col_ln[n*DD + tid];
        __syncthreads();
        float acc = 0.f;
        #pragma unroll 4
        for (int d = 0; d < DD; ++d) acc += rowv[d] * diw[d*512 + 256 + tid];
        int nt = n >> 4, lr = n & 15;
        int kc = tid >> 4, lq = (tid >> 2) & 3, j = tid & 3;
        ((_Float16*)(ws + WS_CW16))[((kc*16 + nt)*64 + lq*16 + lr)*4 + j] = (_Float16)acc;
    } else {
        int p = blk - 256;
        const float* lnp = (const float*)(ws + WS_LNP);
        rowv[tid] = lnp[p*DD + tid];
        __syncthreads();
        float acc = 0.f;
        #pragma unroll 4
        for (int k = 0; k < DD; ++k) acc += rowv[k] * diw[tid*512 + k];
        ((float*)(ws + WS_BASE))[p*DD + tid] = acc + dib[tid] + emb_prompt[p*DD + tid];
    }
}

// base_logits[p][n] = sum_d base[p][d] * col_ln[n][d]
__global__ __launch_bounds__(256) void k0c(char* __restrict__ ws)
{
    __shared__ float bs[DD];
    int p = blockIdx.x, n = threadIdx.x;
    const float* base   = (const float*)(ws + WS_BASE);
    const float* col_ln = (const float*)(ws + WS_COL_LN);
    bs[n] = base[p*DD + n];
    __syncthreads();
    float acc = 0.f;
    #pragma unroll 4
    for (int d = 0; d < DD; ++d) acc += bs[d] * col_ln[n*DD + d];
    ((float*)(ws + WS_BLOG))[p*DD + n] = acc;
}

// ============================ main kernel ============================
// 1 block = 1 batch (grid 1024, 512 thr, 8 waves, 1 block/CU by LDS).
// Wave w owns p-rows [16w,16w+16) x all 256 d. Flash loop, 4 n-chunks of 64.
// Per chunk: CW slice staged to LDS (reg-staged, loads issued early),
// xe slice COMPUTED on the fly into LDS fragment buffer (never HBM),
// double-buffered; single barrier per chunk. MFMA operands: A from LDS
// (ds_read_b64, conflict-free), B (prev rows, P) in registers.
__global__ __launch_bounds__(512, 2) void trompt_main(
    const float* __restrict__ x, const float* __restrict__ prev,
    const float* __restrict__ expand_w, const float* __restrict__ expand_b,
    const float* __restrict__ ln_emb_g, const float* __restrict__ ln_emb_b,
    const char* __restrict__ ws, float* __restrict__ out)
{
    extern __shared__ char smem[];
    float* x_s  = (float*)(smem);
    float* g_s  = (float*)(smem + 1024);
    float* bb_s = (float*)(smem + 2048);

    const char*  cwbase = ws + WS_CW16;
    const half2* WB     = (const half2*)(ws + WS_WB16);   // [n][d] {w,b}

    int b = blockIdx.x;
    int tid = threadIdx.x;
    int w = tid >> 6, l = tid & 63, lq = l >> 4, lr = l & 15;
    int p = 16*w + lr;

    if (tid < 256) {
        x_s[tid]  = x[b*NCOLS + tid];
        g_s[tid]  = ln_emb_g[tid];
        bb_s[tid] = ln_emb_b[tid];
    }

    // prev row -> f16 B-fragments (32 VGPRs), live across all chunks
    half4 pfrag[16];
    {
        const float* prow = prev + ((size_t)b*NP + p)*DD + 4*lq;
        #pragma unroll
        for (int kc = 0; kc < 16; ++kc) {
            f32x4 v = *(const f32x4*)(prow + 16*kc);
            half4 h;
            #pragma unroll
            for (int j = 0; j < 4; ++j) h[j] = (_Float16)v[j];
            pfrag[kc] = h;
        }
    }

    // CW chunk staging: 32 KB -> LDS. 64 B/thread as 4x16B.
    // frag (kc*16 + 4c + nt) -> lds kc*2048 + nt*512 + lane*8
    auto stage_cw = [&](int c, char* dstbuf) {
        #pragma unroll
        for (int i = 0; i < 4; ++i) {
            int u = tid + 512*i;                  // 0..2047
            int kc = u >> 7, rem = u & 127;
            uint4 v = *(const uint4*)(cwbase + kc*8192 + c*2048 + rem*16);
            *(uint4*)(dstbuf + u*16) = v;
        }
    };

    // xe chunk compute: 64 n-rows of LN(relu(x*w+b)) -> f16 fragment buffer.
    // chunk-local n = 16*kc2 + 4*lq2 + j; frag (kc2*16+dt) at byte
    // (((kc2*16+dt)*64) + lq2*16 + lr)*8, j packed in the half4.
    auto compute_xe = [&](int c, char* xebuf) {
        #pragma unroll
        for (int gi = 0; gi < 2; ++gi) {
            int g = w + 8*gi;                     // 0..15
            int kc2 = g >> 2, lq2 = g & 3;
            float vj[4][4];                       // [j][cc]
            #pragma unroll
            for (int j = 0; j < 4; ++j) {
                int n = c*64 + 16*kc2 + 4*lq2 + j;
                float xv = x_s[n];
                const half2* wbrow = WB + n*DD;
                float s = 0.f, q = 0.f;
                #pragma unroll
                for (int cc = 0; cc < 4; ++cc) {
                    half2 pp = wbrow[l + 64*cc];
                    float e = fmaf(xv, (float)pp[0], (float)pp[1]);
                    e = e > 0.f ? e : 0.f;
                    vj[j][cc] = e; s += e; q += e*e;
                }
                #pragma unroll
                for (int off = 32; off; off >>= 1) { s += __shfl_xor(s, off); q += __shfl_xor(q, off); }
                float mu = s * (1.0f/DD);
                float rs = rsqrtf(q*(1.0f/DD) - mu*mu + 1e-5f);
                #pragma unroll
                for (int cc = 0; cc < 4; ++cc) {
                    int d = l + 64*cc;
                    vj[j][cc] = (vj[j][cc]-mu)*rs*g_s[d] + bb_s[d];
                }
            }
            #pragma unroll
            for (int cc = 0; cc < 4; ++cc) {
                int dt = 4*cc + (l >> 4);
                half4 h;
                #pragma unroll
                for (int j = 0; j < 4; ++j) h[j] = (_Float16)vj[j][cc];
                *(half4*)(xebuf + (((kc2*16 + dt)*64) + lq2*16 + lr)*8) = h;
            }
        }
    };

    // prologue: buf0 = CW(0) + xe(0)
    stage_cw(0, smem + LDS_CW0);
    __syncthreads();                 // x_s ready (and CW0 written)
    compute_xe(0, smem + LDS_XE0);

    f32x4 acc_v[16];
    #pragma unroll
    for (int dt = 0; dt < 16; ++dt) acc_v[dt] = (f32x4){0.f,0.f,0.f,0.f};
    float m = -1e30f, ll = 0.f;

    const float* blrow = (const float*)(ws + WS_BLOG) + (size_t)p*DD + 4*lq;

    __syncthreads();                 // buf0 complete

    for (int c = 0; c < 4; ++c) {
        char* cwc = smem + ((c & 1) ? LDS_CW1 : LDS_CW0);
        char* xec = smem + ((c & 1) ? LDS_XE1 : LDS_XE0);
        char* cwn = smem + ((c & 1) ? LDS_CW0 : LDS_CW1);
        char* xen = smem + ((c & 1) ? LDS_XE0 : LDS_XE1);

        // issue next chunk's CW global loads early (land during logits MFMA)
        uint4 st[4];
        if (c < 3) {
            #pragma unroll
            for (int i = 0; i < 4; ++i) {
                int u = tid + 512*i;
                int kc = u >> 7, rem = u & 127;
                st[i] = *(const uint4*)(cwbase + kc*8192 + (c+1)*2048 + rem*16);
            }
        }

        // ---- logits chunk: 16p x 64n, C-init from base_logits ----
        f32x4 acc_c[4];
        #pragma unroll
        for (int nt = 0; nt < 4; ++nt) acc_c[nt] = *(const f32x4*)(blrow + 64*c + 16*nt);
        const char* cwl = cwc + l*8;
        #pragma unroll
        for (int kc = 0; kc < 16; ++kc) {
            const char* fb = cwl + kc*2048;
            half4 a0 = *(const half4*)(fb);
            half4 a1 = *(const half4*)(fb + 512);
            half4 a2 = *(const half4*)(fb + 1024);
            half4 a3 = *(const half4*)(fb + 1536);
            half4 bp = pfrag[kc];
            acc_c[0] = MFMA16(a0, bp, acc_c[0]);
            acc_c[1] = MFMA16(a1, bp, acc_c[1]);
            acc_c[2] = MFMA16(a2, bp, acc_c[2]);
            acc_c[3] = MFMA16(a3, bp, acc_c[3]);
        }

        // ---- online softmax update (p lane-local across lq: 2 shfls) ----
        float pmax = -1e30f;
        #pragma unroll
        for (int nt = 0; nt < 4; ++nt)
            #pragma unroll
            for (int r = 0; r < 4; ++r) pmax = fmaxf(pmax, acc_c[nt][r]);
        pmax = fmaxf(pmax, __shfl_xor(pmax, 16));
        pmax = fmaxf(pmax, __shfl_xor(pmax, 32));
        float mnew = fmaxf(m, pmax);
        float f = __expf(m - mnew);
        m = mnew;
        ll *= f;
        #pragma unroll
        for (int dt = 0; dt < 16; ++dt)
            #pragma unroll
            for (int r = 0; r < 4; ++r) acc_v[dt][r] *= f;

        float csum = 0.f;
        half4 p16c[4];
        #pragma unroll
        for (int nt = 0; nt < 4; ++nt) {
            half4 h;
            #pragma unroll
            for (int r = 0; r < 4; ++r) {
                float e = __expf(acc_c[nt][r] - m);
                csum += e;
                h[r] = (_Float16)e;
            }
            p16c[nt] = h;
        }
        csum += __shfl_xor(csum, 16);
        csum += __shfl_xor(csum, 32);
        ll += csum;

        // ---- fill next chunk's buffer (nobody reads it this chunk) ----
        if (c < 3) {
            compute_xe(c+1, xen);
            #pragma unroll
            for (int i = 0; i < 4; ++i) {
                int u = tid + 512*i;
                *(uint4*)(cwn + u*16) = st[i];
            }
        }

        // ---- PV: acc_v += xe_chunk^T @ P_chunk (A-frags from LDS) ----
        const char* xel = xec + l*8;
        #pragma unroll
        for (int kc2 = 0; kc2 < 4; ++kc2) {
            half4 bp = p16c[kc2];
            const char* xb = xel + kc2*8192;
            #pragma unroll
            for (int dt = 0; dt < 16; ++dt) {
                half4 a = *(const half4*)(xb + dt*512);
                acc_v[dt] = MFMA16(a, bp, acc_v[dt]);
            }
        }

        __syncthreads();             // chunk done; next buffer complete
    }

    // epilogue: out = (V/ll)*sw + sb; col p = lane lr, rows d = 16dt+4lq+r
    {
        float sw = (1.0f + expand_w[p]) / ll;
        float sb = expand_b[p];
        float* orow = out + ((size_t)b*NP + p)*DD + 4*lq;
        #pragma unroll
        for (int dt = 0; dt < 16; ++dt) {
            f32x4 v = acc_v[dt];
            #pragma unroll
            for (int r = 0; r < 4; ++r) v[r] = v[r]*sw + sb;
            *(f32x4*)(orow + 16*dt) = v;
        }
    }
}

// ============================ launcher ============================
extern "C" void kernel_launch(void* const* d_in, const int* in_sizes, int n_in,
                              void* d_out, int out_size, void* d_ws, size_t ws_size,
                              hipStream_t stream) {
    (void)in_sizes; (void)n_in; (void)out_size; (void)ws_size;
    const float* x           = (const float*)d_in[0];
    const float* prev        = (const float*)d_in[1];
    const float* few         = (const float*)d_in[2];
    const float* feb         = (const float*)d_in[3];
    const float* ln_emb_g    = (const float*)d_in[4];
    const float* ln_emb_b    = (const float*)d_in[5];
    const float* ln_col_g    = (const float*)d_in[6];
    const float* ln_col_b    = (const float*)d_in[7];
    const float* ln_prompt_g = (const float*)d_in[8];
    const float* ln_prompt_b = (const float*)d_in[9];
    const float* diw         = (const float*)d_in[10];
    const float* dib         = (const float*)d_in[11];
    const float* emb_column  = (const float*)d_in[12];
    const float* emb_prompt  = (const float*)d_in[13];
    const float* expand_w    = (const float*)d_in[14];
    const float* expand_b    = (const float*)d_in[15];
    char* ws = (char*)d_ws;
    float* out = (float*)d_out;

    k0a<<<512, 256, 0, stream>>>(emb_column, emb_prompt, ln_col_g, ln_col_b,
                                 ln_prompt_g, ln_prompt_b, few, feb, ws);
    k0b<<<384, 256, 0, stream>>>(diw, dib, emb_prompt, ws);
    k0c<<<128, 256, 0, stream>>>(ws);

    (void)hipFuncSetAttribute(reinterpret_cast<const void*>(trompt_main),
                              hipFuncAttributeMaxDynamicSharedMemorySize, SMEM_MAIN);
    trompt_main<<<1024, 512, SMEM_MAIN, stream>>>(x, prev, expand_w, expand_b,
                                                  ln_emb_g, ln_emb_b, ws, out);
}